// Round 1
// baseline (587.135 us; speedup 1.0000x reference)
//
#include <hip/hip_runtime.h>

#define FIN 512
#define FHID 16
#define FOUT 40

// ---------------- degree / dinv ----------------

__global__ void k_deg_init(float* __restrict__ deg, int n) {
    int i = blockIdx.x * blockDim.x + threadIdx.x;
    if (i < n) deg[i] = 1.0f;  // self-loop
}

__global__ void k_deg_count(const int* __restrict__ dst, float* __restrict__ deg, int E) {
    int e = blockIdx.x * blockDim.x + threadIdx.x;
    if (e < E) atomicAdd(&deg[dst[e]], 1.0f);
}

__global__ void k_rsqrt(float* __restrict__ deg, int n) {
    int i = blockIdx.x * blockDim.x + threadIdx.x;
    if (i < n) deg[i] = rsqrtf(deg[i]);  // deg >= 1 always
}

// ---------------- layer 1 GEMM: g = (x @ W1) * dinv, agg init = g ----------------

__global__ __launch_bounds__(256) void k_gemm1(const float* __restrict__ x,
                                               const float* __restrict__ W1,
                                               const float* __restrict__ dinv,
                                               float* __restrict__ g,
                                               float* __restrict__ agg, int n) {
    __shared__ float Wl[FIN * FHID];  // 32 KiB
    {
        const float4* Wv = reinterpret_cast<const float4*>(W1);
        float4* Lv = reinterpret_cast<float4*>(Wl);
        for (int i = threadIdx.x; i < FIN * FHID / 4; i += 256) Lv[i] = Wv[i];
    }
    __syncthreads();

    int row = blockIdx.x * 256 + threadIdx.x;
    if (row >= n) return;

    float acc[FHID];
#pragma unroll
    for (int o = 0; o < FHID; ++o) acc[o] = 0.0f;

    const float4* xr = reinterpret_cast<const float4*>(x + (size_t)row * FIN);
#pragma unroll 2
    for (int k4 = 0; k4 < FIN / 4; ++k4) {
        float4 xv = xr[k4];
#pragma unroll
        for (int j = 0; j < 4; ++j) {
            float xs = (&xv.x)[j];
            const float* wrow = &Wl[(k4 * 4 + j) * FHID];
#pragma unroll
            for (int o = 0; o < FHID; ++o) acc[o] = fmaf(xs, wrow[o], acc[o]);
        }
    }

    float dv = dinv[row];
    float4* gp = reinterpret_cast<float4*>(g + (size_t)row * FHID);
    float4* ap = reinterpret_cast<float4*>(agg + (size_t)row * FHID);
#pragma unroll
    for (int q = 0; q < FHID / 4; ++q) {
        float4 v;
        v.x = acc[4 * q + 0] * dv;
        v.y = acc[4 * q + 1] * dv;
        v.z = acc[4 * q + 2] * dv;
        v.w = acc[4 * q + 3] * dv;
        gp[q] = v;
        ap[q] = v;
    }
}

// ---------------- edge scatter: agg[dst] += g[src], 16 lanes per edge ----------------

__global__ void k_scatter16(const int* __restrict__ src, const int* __restrict__ dst,
                            const float* __restrict__ g, float* __restrict__ agg,
                            int E) {
    long long tid = (long long)blockIdx.x * blockDim.x + threadIdx.x;
    int e = (int)(tid >> 4);
    int c = (int)(tid & 15);
    if (e >= E) return;
    int s = src[e];
    int d = dst[e];
    float v = g[(size_t)s * FHID + c];
    atomicAdd(&agg[(size_t)d * FHID + c], v);
}

// ---------------- finish layer 1: p = relu(agg*dinv + b1) * dinv; g<-p, agg<-p ----------------

__global__ void k_finish1(float* __restrict__ g, float* __restrict__ agg,
                          const float* __restrict__ dinv, const float* __restrict__ b1,
                          int n) {
    int row = blockIdx.x * blockDim.x + threadIdx.x;
    if (row >= n) return;
    float dv = dinv[row];
    float4* ap = reinterpret_cast<float4*>(agg + (size_t)row * FHID);
    float4* gp = reinterpret_cast<float4*>(g + (size_t)row * FHID);
    const float4* bv = reinterpret_cast<const float4*>(b1);
#pragma unroll
    for (int q = 0; q < FHID / 4; ++q) {
        float4 v = ap[q];
        float4 b = bv[q];
        float4 r;
        r.x = fmaxf(fmaf(v.x, dv, b.x), 0.0f) * dv;
        r.y = fmaxf(fmaf(v.y, dv, b.y), 0.0f) * dv;
        r.z = fmaxf(fmaf(v.z, dv, b.z), 0.0f) * dv;
        r.w = fmaxf(fmaf(v.w, dv, b.w), 0.0f) * dv;
        ap[q] = r;
        gp[q] = r;
    }
}

// ---------------- finish layer 2: out = log_softmax((aggp*dinv) @ W2 + b2) ----------------

__global__ __launch_bounds__(256) void k_finish2(const float* __restrict__ aggp,
                                                 const float* __restrict__ dinv,
                                                 const float* __restrict__ W2,
                                                 const float* __restrict__ b2,
                                                 float* __restrict__ out, int n) {
    __shared__ float Wl[FHID * FOUT];  // 2.5 KiB
    __shared__ float bl[FOUT];
    for (int i = threadIdx.x; i < FHID * FOUT; i += 256) Wl[i] = W2[i];
    for (int i = threadIdx.x; i < FOUT; i += 256) bl[i] = b2[i];
    __syncthreads();

    int row = blockIdx.x * 256 + threadIdx.x;
    if (row >= n) return;

    float dv = dinv[row];
    float q[FHID];
    const float4* ap = reinterpret_cast<const float4*>(aggp + (size_t)row * FHID);
#pragma unroll
    for (int t = 0; t < FHID / 4; ++t) {
        float4 v = ap[t];
        q[4 * t + 0] = v.x * dv;
        q[4 * t + 1] = v.y * dv;
        q[4 * t + 2] = v.z * dv;
        q[4 * t + 3] = v.w * dv;
    }

    float acc[FOUT];
#pragma unroll
    for (int o = 0; o < FOUT; ++o) acc[o] = bl[o];
#pragma unroll
    for (int k = 0; k < FHID; ++k) {
        float qs = q[k];
        const float* wrow = &Wl[k * FOUT];
#pragma unroll
        for (int o = 0; o < FOUT; ++o) acc[o] = fmaf(qs, wrow[o], acc[o]);
    }

    // log_softmax
    float m = acc[0];
#pragma unroll
    for (int o = 1; o < FOUT; ++o) m = fmaxf(m, acc[o]);
    float ssum = 0.0f;
#pragma unroll
    for (int o = 0; o < FOUT; ++o) ssum += expf(acc[o] - m);
    float lse = m + logf(ssum);

    float4* op = reinterpret_cast<float4*>(out + (size_t)row * FOUT);
#pragma unroll
    for (int t = 0; t < FOUT / 4; ++t) {
        float4 v;
        v.x = acc[4 * t + 0] - lse;
        v.y = acc[4 * t + 1] - lse;
        v.z = acc[4 * t + 2] - lse;
        v.w = acc[4 * t + 3] - lse;
        op[t] = v;
    }
}

// ---------------- launch ----------------

extern "C" void kernel_launch(void* const* d_in, const int* in_sizes, int n_in,
                              void* d_out, int out_size, void* d_ws, size_t ws_size,
                              hipStream_t stream) {
    const float* x  = (const float*)d_in[0];
    const int*   ei = (const int*)d_in[1];   // int32: [2, E], row 0 = src, row 1 = dst
    const float* W1 = (const float*)d_in[2];
    const float* b1 = (const float*)d_in[3];
    const float* W2 = (const float*)d_in[4];
    const float* b2 = (const float*)d_in[5];

    const int fh = in_sizes[3];              // 16
    const int fi = in_sizes[2] / fh;         // 512
    const int n  = in_sizes[0] / fi;         // 100000
    const int E  = in_sizes[1] / 2;          // 3200000
    (void)n_in; (void)out_size; (void)ws_size;

    const int* src = ei;
    const int* dst = ei + E;

    float* ws   = (float*)d_ws;
    float* dinv = ws;                          // n floats
    float* g    = ws + n;                      // 16n floats (g1, then p)
    float* agg  = ws + n + (size_t)FHID * n;   // 16n floats (agg1, then aggp)

    float* out = (float*)d_out;

    const int TB = 256;
    const int nb_n = (n + TB - 1) / TB;
    const int nb_e = (E + TB - 1) / TB;
    const long long tscat = (long long)E * FHID;
    const int nb_s = (int)((tscat + TB - 1) / TB);

    k_deg_init<<<nb_n, TB, 0, stream>>>(dinv, n);
    k_deg_count<<<nb_e, TB, 0, stream>>>(dst, dinv, E);
    k_rsqrt<<<nb_n, TB, 0, stream>>>(dinv, n);

    // layer 1
    k_gemm1<<<nb_n, TB, 0, stream>>>(x, W1, dinv, g, agg, n);
    k_scatter16<<<nb_s, TB, 0, stream>>>(src, dst, g, agg, E);
    k_finish1<<<nb_n, TB, 0, stream>>>(g, agg, dinv, b1, n);

    // layer 2 (aggregate in 16-dim space, then transform)
    k_scatter16<<<nb_s, TB, 0, stream>>>(src, dst, g, agg, E);
    k_finish2<<<nb_n, TB, 0, stream>>>(agg, dinv, W2, b2, out, n);
}